// Round 1
// baseline (278.386 us; speedup 1.0000x reference)
//
#include <hip/hip_runtime.h>
#include <hip/hip_bf16.h>
#include <cstdint>

typedef unsigned short u16;
typedef __bf16 bf16x8 __attribute__((ext_vector_type(8)));
typedef float floatx4 __attribute__((ext_vector_type(4)));

#define AS1 __attribute__((address_space(1)))
#define AS3 __attribute__((address_space(3)))

// round-to-nearest-even f32 -> bf16 bits
static __device__ __forceinline__ u16 f2bf(float f) {
    union { float f; unsigned int u; } v; v.f = f;
    unsigned int u = v.u;
    return (u16)((u + 0x7FFFu + ((u >> 16) & 1u)) >> 16);
}

// raw barrier: no implicit vmcnt drain (that drain is the m97-class stall).
// sched_barrier(0) pins machine-sched motion; empty asm blocks IR-level motion
// of LDS/global ops across the barrier.
static __device__ __forceinline__ void bar() {
    __builtin_amdgcn_sched_barrier(0);
    asm volatile("" ::: "memory");
    __builtin_amdgcn_s_barrier();
    asm volatile("" ::: "memory");
    __builtin_amdgcn_sched_barrier(0);
}

// ---------------------------------------------------------------------------
// Fused prep kernel (unchanged): blockIdx-partitioned into
//   [0, 4096)      : transpose+cvt w1 (1024x4096 -> W1t[4096][1024])
//   [4096, 8192)   : transpose+cvt w2 (4096x1024 -> W2t[1024][4096])
//   [8192, 16384)  : LayerNorm row (act row -> X row, bf16)
// ---------------------------------------------------------------------------
__device__ __forceinline__ void transpose_body(
    const float* __restrict__ in, u16* __restrict__ out,
    int R, int Ccols, int bx, int by, int tid, float (*tile)[33])
{
    const int tx = tid & 31;
    const int ty = tid >> 5;    // 0..7
    const int c0 = bx * 32;
    const int r0 = by * 32;
#pragma unroll
    for (int i = 0; i < 32; i += 8)
        tile[ty + i][tx] = in[(size_t)(r0 + ty + i) * Ccols + (c0 + tx)];
    __syncthreads();
#pragma unroll
    for (int i = 0; i < 32; i += 8)
        out[(size_t)(c0 + ty + i) * R + (r0 + tx)] = f2bf(tile[tx][ty + i]);
}

__global__ __launch_bounds__(256)
void prep(const float* __restrict__ w1, const float* __restrict__ w2,
          const float* __restrict__ act, const float* __restrict__ ln_scale,
          const float* __restrict__ ln_bias,
          u16* __restrict__ W1t, u16* __restrict__ W2t, u16* __restrict__ X)
{
    __shared__ float smem[32][33];   // transpose tile; LN uses first 8 floats
    const int id  = blockIdx.x;
    const int tid = threadIdx.x;

    if (id < 4096) {
        transpose_body(w1, W1t, 1024, 4096, id & 127, id >> 7, tid, smem);
        return;
    }
    if (id < 8192) {
        const int t = id - 4096;
        transpose_body(w2, W2t, 4096, 1024, t & 31, t >> 5, tid, smem);
        return;
    }
    // LayerNorm, one block per row
    const int row = id - 8192;
    const float4 v = ((const float4*)(act + (size_t)row * 1024))[tid];
    float s  = v.x + v.y + v.z + v.w;
    float ss = v.x * v.x + v.y * v.y + v.z * v.z + v.w * v.w;
#pragma unroll
    for (int off = 32; off > 0; off >>= 1) {
        s  += __shfl_xor(s, off, 64);
        ss += __shfl_xor(ss, off, 64);
    }
    float* red = &smem[0][0];
    const int wave = tid >> 6, lane = tid & 63;
    if (lane == 0) { red[wave] = s; red[4 + wave] = ss; }
    __syncthreads();
    s  = red[0] + red[1] + red[2] + red[3];
    ss = red[4] + red[5] + red[6] + red[7];
    const float mu  = s * (1.0f / 1024.0f);
    const float var = ss * (1.0f / 1024.0f) - mu * mu;
    const float rs  = rsqrtf(var + 1e-5f);
    const float4 sc = ((const float4*)ln_scale)[tid];
    const float4 bi = ((const float4*)ln_bias)[tid];
    ushort4 o;
    o.x = f2bf((v.x - mu) * rs * sc.x + bi.x);
    o.y = f2bf((v.y - mu) * rs * sc.y + bi.y);
    o.z = f2bf((v.z - mu) * rs * sc.z + bi.z);
    o.w = f2bf((v.w - mu) * rs * sc.w + bi.w);
    ((ushort4*)(X + (size_t)row * 1024))[tid] = o;
}

// ---------------------------------------------------------------------------
// R7: pipelined bf16 GEMM, T3+T4+T5 structure (counted-vmcnt, raw barriers,
// setprio) on a 256x128 tile.
//
//   C[M][N] = A[M][K] * Bt[N][K]^T + bias (+ReLU)
//
// Geometry: BM=256, BN=128, BK=64; 512 thr = 8 waves (4 wm x 2 wn), per-wave
// 64x64 out = acc[4][4] (64 VGPR). Per phase (2 phases/K-tile): 8 ds_read_b128
// + 3 global_load_lds issues + raw bar + 16 MFMA (setprio-wrapped).
//
// Pipeline: TRIPLE-buffered LDS (3 x (32KB A + 16KB B) = 144KB, 1 block/CU).
// While computing tile t (buf t%3), tile t+2 is staged into buf (t+2)%3 =
// buf (t-1)%3, whose readers all finished before tile t began (barrier) ->
// race-free by construction, no sub-region analysis needed. Boundary wait is
// s_waitcnt vmcnt(6) (= t+2's 6 issues in flight; guarantees t+1 resident).
// Never vmcnt(0) in steady state -> loads live across barriers (the R2/m97
// barrier-drain stall is gone).
//
// Staging swizzle (proven 0-conflict in R2..R6 kernel): row's 16B slot s
// stores global slot s ^ (row&7); frag read uses slot (4*kk+quad)^(l16&7).
// global_load_lds dest = wave-uniform base + lane*16 (linear) as required.
//
// Grids: GEMM1 (N=4096): 32x32=1024 blocks = 4 clean rounds at 1 block/CU.
//        GEMM2 (N=1024): 32x8 = 256 blocks = exactly 1/CU, tail-free
//        (BN=256 would give 128 blocks = half the GPU idle).
// Requires: M%256==0, N%128==0, K%64==0, K>=128.
// ---------------------------------------------------------------------------
template <bool BF16_OUT, bool RELU>
__global__ __launch_bounds__(512, 2)
void gemm256(const u16* __restrict__ A,      // [M][K] bf16 bits
             const u16* __restrict__ Bt,     // [N][K] bf16 bits
             const float* __restrict__ bias, // [N]
             void* __restrict__ Cout,
             int M, int N, int K)
{
    constexpr int BM = 256, BN = 128, BK = 64;
    constexpr int ASZ = BM * BK;   // 16384 u16 = 32KB
    constexpr int BSZ = BN * BK;   //  8192 u16 = 16KB
    __shared__ __align__(16) u16 Alds[3 * ASZ];   // 96KB
    __shared__ __align__(16) u16 Blds[3 * BSZ];   // 48KB

    const int tid  = threadIdx.x;
    const int wave = tid >> 6;
    const int lane = tid & 63;
    const int srow = lane >> 3;     // staging: row within 8-row chunk
    const int s_st = lane & 7;      // staging: stored 16B slot
    const int quad = lane >> 4;
    const int l16  = lane & 15;
    const int rkey = l16 & 7;       // read-side swizzle key (row&7)
    const int wm   = wave >> 1;     // 0..3 -> 64-row stripe
    const int wn   = wave & 1;      // 0..1 -> 64-col stripe

    const int nbm = M >> 8;
    const int id  = blockIdx.x;
    const int bm  = id % nbm;       // bm-fastest (R5: swizzles hurt; keep)
    const int bn  = id / nbm;

    const u16* Ag = A  + (size_t)bm * BM * K;
    const u16* Bg = Bt + (size_t)bn * BN * K;

    // one issue = 512 lanes... per wave: 64 lanes x 16B = 1KB = 8 rows.
    // A: 32 chunks (4/wave), B: 16 chunks (2/wave).
    auto stageA = [&](int r, int k0, int ab) {
        const int ca  = wave * 4 + r;
        const int row = ca * 8 + srow;
        const int col = (s_st ^ (row & 7)) * 8;
        __builtin_amdgcn_global_load_lds(
            (AS1 void*)(Ag + (size_t)row * K + k0 + col),
            (AS3 void*)(&Alds[ab + ca * 512]), 16, 0, 0);
    };
    auto stageB = [&](int r, int k0, int bb) {
        const int cb  = wave * 2 + r;
        const int row = cb * 8 + srow;
        const int col = (s_st ^ (row & 7)) * 8;
        __builtin_amdgcn_global_load_lds(
            (AS1 void*)(Bg + (size_t)row * K + k0 + col),
            (AS3 void*)(&Blds[bb + cb * 512]), 16, 0, 0);
    };

    floatx4 acc[4][4];
#pragma unroll
    for (int i = 0; i < 4; ++i)
#pragma unroll
        for (int j = 0; j < 4; ++j)
            acc[i][j] = (floatx4){0.f, 0.f, 0.f, 0.f};

    const int NT = K >> 6;

    // prologue: t0 -> buf0, t1 -> buf1 (12 issues/wave); wait t0 only.
#pragma unroll
    for (int r = 0; r < 4; ++r) stageA(r, 0, 0);
#pragma unroll
    for (int r = 0; r < 2; ++r) stageB(r, 0, 0);
#pragma unroll
    for (int r = 0; r < 4; ++r) stageA(r, BK, ASZ);
#pragma unroll
    for (int r = 0; r < 2; ++r) stageB(r, BK, BSZ);
    asm volatile("s_waitcnt vmcnt(6)" ::: "memory");
    bar();

    int bsel = 0;                   // t % 3
    for (int t = 0; t < NT; ++t) {
        const int ab  = bsel * ASZ;
        const int bb  = bsel * BSZ;
        const int bs2 = (bsel >= 1) ? bsel - 1 : 2;   // (t+2) % 3
        const int ab2 = bs2 * ASZ;
        const int bb2 = bs2 * BSZ;
        const bool do_stage = (t + 2 < NT);
        const int  k2 = (t + 2) << 6;

#pragma unroll
        for (int kk = 0; kk < 2; ++kk) {
            // frag reads for this phase (k-half kk), swizzled slots
            const int slot = ((kk * 4 + quad) ^ rkey) * 8;
            bf16x8 afr[4], bfr[4];
#pragma unroll
            for (int i = 0; i < 4; ++i) {
                afr[i] = *(const bf16x8*)
                    &Alds[ab + (wm * 64 + i * 16 + l16) * 64 + slot];
                bfr[i] = *(const bf16x8*)
                    &Blds[bb + (wn * 64 + i * 16 + l16) * 64 + slot];
            }
            // stage tile t+2 into the buffer tile t-1 vacated (race-free)
            if (do_stage) {
                stageA(kk * 2 + 0, k2, ab2);
                stageA(kk * 2 + 1, k2, ab2);
                stageB(kk, k2, bb2);
            }
            bar();
            __builtin_amdgcn_s_setprio(1);
#pragma unroll
            for (int mi = 0; mi < 4; ++mi)
#pragma unroll
                for (int ni = 0; ni < 4; ++ni)
                    acc[mi][ni] = __builtin_amdgcn_mfma_f32_16x16x32_bf16(
                        bfr[ni], afr[mi], acc[mi][ni], 0, 0, 0);
            __builtin_amdgcn_s_setprio(0);
            if (kk == 1) {
                // tile boundary: t+1 must be resident for next phase's reads.
                // Counted wait: t+2's 6 issues may stay in flight.
                if (do_stage)
                    asm volatile("s_waitcnt vmcnt(6)" ::: "memory");
                else if (t + 1 < NT)
                    asm volatile("s_waitcnt vmcnt(0)" ::: "memory");
            }
            bar();
        }
        bsel = (bsel == 2) ? 0 : bsel + 1;
    }

    // epilogue: lane (l16, quad) of acc[mi][ni] holds
    //   C[m = mbase+mi*16+l16][n = nbase+ni*16+quad*4 + r], r=0..3 contiguous
    const int mbase = bm * BM + wm * 64;
    const int nbase = bn * BN + wn * 64;
#pragma unroll
    for (int mi = 0; mi < 4; ++mi) {
        const int m = mbase + mi * 16 + l16;
#pragma unroll
        for (int ni = 0; ni < 4; ++ni) {
            const int n0 = nbase + ni * 16 + quad * 4;
            const float4 bv = *(const float4*)&bias[n0];
            float v0 = acc[mi][ni][0] + bv.x;
            float v1 = acc[mi][ni][1] + bv.y;
            float v2 = acc[mi][ni][2] + bv.z;
            float v3 = acc[mi][ni][3] + bv.w;
            if (RELU) {
                v0 = fmaxf(v0, 0.f); v1 = fmaxf(v1, 0.f);
                v2 = fmaxf(v2, 0.f); v3 = fmaxf(v3, 0.f);
            }
            if (BF16_OUT) {
                ushort4 o = { f2bf(v0), f2bf(v1), f2bf(v2), f2bf(v3) };
                *(ushort4*)&((u16*)Cout)[(size_t)m * N + n0] = o;
            } else {
                float4 o = { v0, v1, v2, v3 };
                *(float4*)&((float*)Cout)[(size_t)m * N + n0] = o;
            }
        }
    }
}

// ---------------------------------------------------------------------------
// inputs: 0 act(4,2048,1024) f32, 1 mask(unused), 2 ln_scale(1024),
//         3 ln_bias(1024), 4 w1(1024,4096), 5 b1(4096), 6 w2(4096,1024),
//         7 b2(1024). out: (4,2048,1024) f32.
// ws layout (bf16 bits): X[8192*1024] | W1t[4096*1024] | W2t[1024*4096] |
//                        H[8192*4096]  -> 100,663,296 bytes total
// ---------------------------------------------------------------------------
extern "C" void kernel_launch(void* const* d_in, const int* in_sizes, int n_in,
                              void* d_out, int out_size, void* d_ws, size_t ws_size,
                              hipStream_t stream)
{
    const float* act      = (const float*)d_in[0];
    const float* ln_scale = (const float*)d_in[2];
    const float* ln_bias  = (const float*)d_in[3];
    const float* w1       = (const float*)d_in[4];
    const float* b1       = (const float*)d_in[5];
    const float* w2       = (const float*)d_in[6];
    const float* b2       = (const float*)d_in[7];
    float* out = (float*)d_out;

    const int M = 8192, C = 1024, CI = 4096;

    u16* X   = (u16*)d_ws;                 // [M][C]
    u16* W1t = X   + (size_t)M * C;        // [CI][C]
    u16* W2t = W1t + (size_t)CI * C;       // [C][CI]
    u16* H   = W2t + (size_t)C * CI;       // [M][CI]

    // fused prep: w1/w2 transpose+cvt + layernorm, one launch
    prep<<<16384, 256, 0, stream>>>(w1, w2, act, ln_scale, ln_bias, W1t, W2t, X);
    // H = relu(X @ W1 + b1), bf16.  1024 blocks (1/CU resident, 4 rounds).
    gemm256<true, true><<<(M / 256) * (CI / 128), 512, 0, stream>>>(
        X, W1t, b1, (void*)H, M, CI, C);
    // out = H @ W2 + b2, fp32.  256 blocks = exactly 1/CU, tail-free.
    gemm256<false, false><<<(M / 256) * (C / 128), 512, 0, stream>>>(
        H, W2t, b2, (void*)out, M, C, CI);
}